// Round 5
// baseline (942.209 us; speedup 1.0000x reference)
//
#include <hip/hip_runtime.h>

#define B_ROWS 4096
#define H_DIM  2048
#define L_DIM  16384
#define TOPK   32
#define CAND_CAP 512
#define AMBIG_CAP 128
#define BAND 0.05f          // > 2*e ; e = bf16-input GEMM max |v_hat - v_true| (est 0.0155)
#define COLLECT_THR 2.3f    // v32 ~ N(2.89, 0.058) over rows -> ~10 sigma safe; ~175 cands/row

typedef __attribute__((ext_vector_type(8))) short bf16x8;
typedef __attribute__((ext_vector_type(4))) float f32x4;

__device__ __forceinline__ unsigned short f32_to_bf16(float f) {
  unsigned int u = __float_as_uint(f);
  u += 0x7FFFu + ((u >> 16) & 1u);           // round-to-nearest-even
  return (unsigned short)(u >> 16);
}
__device__ __forceinline__ float bf16_to_f32(unsigned short h) {
  return __uint_as_float(((unsigned int)h) << 16);
}

__device__ __forceinline__ void gload_lds16(const void* g, void* l) {
  __builtin_amdgcn_global_load_lds(
      (const __attribute__((address_space(1))) unsigned int*)g,
      (__attribute__((address_space(3))) unsigned int*)l, 16, 0, 0);
}

// ---------------------------------------------------------------- convert f32 -> bf16
__global__ __launch_bounds__(256) void k_convert(const float* __restrict__ src,
                                                 unsigned short* __restrict__ dst, int n4) {
  int i = blockIdx.x * 256 + threadIdx.x;
  if (i < n4) {
    float4 v = ((const float4*)src)[i];
    ushort4 o;
    o.x = f32_to_bf16(v.x); o.y = f32_to_bf16(v.y);
    o.z = f32_to_bf16(v.z); o.w = f32_to_bf16(v.w);
    ((ushort4*)dst)[i] = o;
  }
}

// ------------------------------------------- W_dec [H, L] f32  ->  WdT [L, H] bf16
__global__ __launch_bounds__(256) void k_transpose(const float* __restrict__ Wd,
                                                   unsigned short* __restrict__ WdT) {
  __shared__ float tile[64][65];              // [l_local][h_local], +1 pad
  int bi = blockIdx.x & 255;                  // l tile (16384/64 = 256)
  int bj = blockIdx.x >> 8;                   // h tile (2048/64 = 32)
  int t = threadIdx.x;
  int l0 = bi * 64, h0 = bj * 64;
#pragma unroll
  for (int p = 0; p < 4; ++p) {
    int hr = p * 16 + (t >> 4);
    int lc = (t & 15) * 4;
    float4 v = *(const float4*)(Wd + (size_t)(h0 + hr) * L_DIM + l0 + lc);
    tile[lc + 0][hr] = v.x; tile[lc + 1][hr] = v.y;
    tile[lc + 2][hr] = v.z; tile[lc + 3][hr] = v.w;
  }
  __syncthreads();
#pragma unroll
  for (int p = 0; p < 2; ++p) {
    int lr = p * 32 + (t >> 3);
    int hc = (t & 7) * 8;
    bf16x8 o;
#pragma unroll
    for (int i = 0; i < 8; ++i) o[i] = (short)f32_to_bf16(tile[lr][hc + i]);
    *(bf16x8*)(WdT + (size_t)(l0 + lr) * H_DIM + h0 + hc) = o;
  }
}

// ------------------------------- encoder GEMM (bf16 MFMA) + fused candidate collect
// R2-proven schedule (3-slot LDS ring, BK=32, counted vmcnt(4)) + R2 XCD swizzle mapping.
// Epilogue: no z_pre store — threshold-collect acc values into (cidx, cvals, ccnt).
__global__ __launch_bounds__(512, 2) void k_gemm(const unsigned short* __restrict__ A,
                                                 const unsigned short* __restrict__ Bm,
                                                 int* __restrict__ cidx,
                                                 float* __restrict__ cvals,
                                                 int* __restrict__ ccnt) {
  __shared__ unsigned short As[3 * 8192];     // 3 x 256x32 bf16 = 48 KB
  __shared__ unsigned short Bs[3 * 8192];     // 48 KB
  const size_t K = H_DIM;
  int bid = blockIdx.x;
  int cpx = gridDim.x >> 3;                   // 1024/8 = 128, bijective (nwg%8==0)
  int swz = (bid & 7) * cpx + (bid >> 3);
  int tm = swz >> 6;                          // 16 M-tiles (XCD-consecutive share A panel)
  int tn = swz & 63;                          // 64 N-tiles
  int t = threadIdx.x;
  int lane = t & 63;
  int w = t >> 6;
  int wm = w >> 2, wn = w & 3;                // 2 x 4 wave grid; per-wave 128x64

  int rloc = lane & 15;
  int kc = lane >> 4;                         // 0..3 : 8-elem K chunk
  int swzk = (kc ^ ((rloc >> 1) & 3)) << 3;   // bank swizzle (2-way max), shorts

  // staging decode: per thread row = j*128 + (t>>2), phys chunk (t&3) holds logical kcs
  int srow = t >> 2;
  int kcs = (t & 3) ^ ((srow >> 1) & 3);      // inverse-permuted global source (rule 21)
  const unsigned short* aS0 = A + (size_t)(tm * 256 + srow) * K + kcs * 8;
  const unsigned short* aS1 = aS0 + 128 * K;
  const unsigned short* bS0 = Bm + (size_t)(tn * 256 + srow) * K + kcs * 8;
  const unsigned short* bS1 = bS0 + 128 * K;
  int dA = t * 8;                             // linear LDS dest (shorts)

  f32x4 acc[8][4];
#pragma unroll
  for (int i = 0; i < 8; ++i)
#pragma unroll
    for (int j = 0; j < 4; ++j) { f32x4 z = {0.f, 0.f, 0.f, 0.f}; acc[i][j] = z; }

#define STAGE_A(kt, sw) { size_t ko = (size_t)(kt) * 32; \
    gload_lds16(aS0 + ko, &As[(sw) * 8192 + dA]); \
    gload_lds16(aS1 + ko, &As[(sw) * 8192 + 4096 + dA]); }
#define STAGE_B(kt, sw) { size_t ko = (size_t)(kt) * 32; \
    gload_lds16(bS0 + ko, &Bs[(sw) * 8192 + dA]); \
    gload_lds16(bS1 + ko, &Bs[(sw) * 8192 + 4096 + dA]); }

  // prologue: stage tile0 + tile1; wait tile0 (4 outstanding allowed)
  STAGE_A(0, 0) STAGE_B(0, 0)
  STAGE_A(1, 1) STAGE_B(1, 1)
  asm volatile("s_waitcnt vmcnt(4)" ::: "memory");
  __builtin_amdgcn_s_barrier();

  int sR = 0;
  const int aBase0 = (wm * 128 + rloc) * 32 + swzk;
  const int bBase0 = (wn * 64 + rloc) * 32 + swzk;
  const int NKT = H_DIM / 32;
  for (int kt = 0; kt < NKT; ++kt) {
    int sW = sR + 2; if (sW >= 3) sW -= 3;
    const unsigned short* Ab = &As[sR * 8192 + aBase0];
    const unsigned short* Bb = &Bs[sR * 8192 + bBase0];
    bool st = (kt + 2 < NKT);                 // wave-uniform
    // ---- phase 0: read A-half0 + all B frags; issue A-stage of tile kt+2
    bf16x8 a0[4], b0[4];
#pragma unroll
    for (int m = 0; m < 4; ++m) a0[m] = *(const bf16x8*)(Ab + m * 512);
#pragma unroll
    for (int n = 0; n < 4; ++n) b0[n] = *(const bf16x8*)(Bb + n * 512);
    if (st) STAGE_A(kt + 2, sW)
    __builtin_amdgcn_s_barrier();
    __builtin_amdgcn_s_setprio(1);
#pragma unroll
    for (int m = 0; m < 4; ++m)
#pragma unroll
      for (int n = 0; n < 4; ++n)
        acc[m][n] = __builtin_amdgcn_mfma_f32_16x16x32_bf16(a0[m], b0[n], acc[m][n], 0, 0, 0);
    __builtin_amdgcn_s_setprio(0);
    __builtin_amdgcn_s_barrier();
    // ---- phase 1: read A-half1 (B reused); issue B-stage of tile kt+2
    bf16x8 a1[4];
#pragma unroll
    for (int m = 0; m < 4; ++m) a1[m] = *(const bf16x8*)(Ab + (m + 4) * 512);
    if (st) STAGE_B(kt + 2, sW)
    __builtin_amdgcn_s_barrier();
    __builtin_amdgcn_s_setprio(1);
#pragma unroll
    for (int m = 0; m < 4; ++m)
#pragma unroll
      for (int n = 0; n < 4; ++n)
        acc[m + 4][n] = __builtin_amdgcn_mfma_f32_16x16x32_bf16(a1[m], b0[n], acc[m + 4][n], 0, 0, 0);
    __builtin_amdgcn_s_setprio(0);
    // ---- tile boundary: counted wait
    if (kt < NKT - 2) { asm volatile("s_waitcnt vmcnt(4)" ::: "memory"); }
    else if (kt == NKT - 2) { asm volatile("s_waitcnt vmcnt(0)" ::: "memory"); }
    __builtin_amdgcn_s_barrier();
    ++sR; if (sR == 3) sR = 0;
  }
#undef STAGE_A
#undef STAGE_B
  // epilogue: fused collect. C/D layout col=lane&15, row=(lane>>4)*4+reg [m89].
  int colg = lane & 15, quad = lane >> 4;
  int rbase = tm * 256 + wm * 128 + quad * 4;
  int cbase = tn * 256 + wn * 64 + colg;
#pragma unroll
  for (int m = 0; m < 8; ++m)
#pragma unroll
    for (int r = 0; r < 4; ++r) {
      int row = rbase + m * 16 + r;
      float v0 = acc[m][0][r], v1 = acc[m][1][r], v2 = acc[m][2][r], v3 = acc[m][3][r];
      int ns = (v0 > COLLECT_THR) + (v1 > COLLECT_THR) + (v2 > COLLECT_THR) + (v3 > COLLECT_THR);
      if (ns) {
        int bse = atomicAdd(&ccnt[row], ns);
        if (v0 > COLLECT_THR) { if (bse < CAND_CAP) { cidx[row * CAND_CAP + bse] = cbase;      cvals[row * CAND_CAP + bse] = v0; } ++bse; }
        if (v1 > COLLECT_THR) { if (bse < CAND_CAP) { cidx[row * CAND_CAP + bse] = cbase + 16; cvals[row * CAND_CAP + bse] = v1; } ++bse; }
        if (v2 > COLLECT_THR) { if (bse < CAND_CAP) { cidx[row * CAND_CAP + bse] = cbase + 32; cvals[row * CAND_CAP + bse] = v2; } ++bse; }
        if (v3 > COLLECT_THR) { if (bse < CAND_CAP) { cidx[row * CAND_CAP + bse] = cbase + 48; cvals[row * CAND_CAP + bse] = v3; } ++bse; }
      }
    }
}

// --------------- fallback: rows with too few candidates (never taken for this data)
// Early-exit if ccnt[b] >= 40. Else recompute row dots (bf16, fp32 acc — consistent
// with gemm values) with descending thresholds until >= 40 or thr == 0.
__global__ __launch_bounds__(256) void k_fallback(const unsigned short* __restrict__ xb,
                                                  const unsigned short* __restrict__ Wb,
                                                  int* __restrict__ cidx,
                                                  float* __restrict__ cvals,
                                                  int* __restrict__ ccnt) {
  int b = blockIdx.x;
  if (ccnt[b] >= 40) return;
  int t = threadIdx.x;
  __shared__ float xs[H_DIM];
  for (int i = t; i < H_DIM / 8; i += 256) {
    bf16x8 v = ((const bf16x8*)(xb + (size_t)b * H_DIM))[i];
#pragma unroll
    for (int q = 0; q < 8; ++q) xs[i * 8 + q] = bf16_to_f32((unsigned short)v[q]);
  }
  float thr = 1.7f;
  for (int pass = 0; pass < 4; ++pass) {
    __syncthreads();
    if (t == 0) ccnt[b] = 0;
    __syncthreads();
    for (int l = t; l < L_DIM; l += 256) {
      const bf16x8* wr = (const bf16x8*)(Wb + (size_t)l * H_DIM);
      float dot = 0.f;
      for (int i = 0; i < H_DIM / 8; ++i) {
        bf16x8 ww = wr[i];
#pragma unroll
        for (int q = 0; q < 8; ++q) dot += bf16_to_f32((unsigned short)ww[q]) * xs[i * 8 + q];
      }
      if (dot > thr) {
        int p = atomicAdd(&ccnt[b], 1);
        if (p < CAND_CAP) { cidx[b * CAND_CAP + p] = l; cvals[b * CAND_CAP + p] = dot; }
      }
    }
    __syncthreads();
    if (ccnt[b] >= 40 || thr <= 0.f) break;   // uniform (all lanes read same global)
    thr -= 0.6f; if (thr < 0.f) thr = 0.f;
  }
}

// ----------------- fused topk: rank -> classify vs b32 -> fp64-rescore AMBIG only ->
//                   emit final 32 (scatter z + selv/seli for decoder)
// SURE-IN  (v_hat > b32+BAND): provably in true top-32 given |v_hat-v_true| <= BAND/2.
// SURE-OUT (v_hat < b32-BAND): provably out. AMBIG band (~4/row) rescored in fp64.
__global__ __launch_bounds__(256) void k_topk(const float* __restrict__ x,
                                              const float* __restrict__ Wenc,
                                              const int* __restrict__ cidx,
                                              const float* __restrict__ cvals,
                                              const int* __restrict__ ccnt,
                                              float* __restrict__ zout,
                                              float* __restrict__ selv,
                                              int* __restrict__ seli) {
  int b = blockIdx.x;
  int t = threadIdx.x;
  __shared__ float xr[H_DIM];                 // 8 KB
  __shared__ float cv[CAND_CAP];
  __shared__ int   ci[CAND_CAP];
  __shared__ float s_b32;
  __shared__ unsigned int s_na, s_nin;
  __shared__ int    ai[AMBIG_CAP];
  __shared__ double ax[AMBIG_CAP];
  int cnt = ccnt[b]; if (cnt > CAND_CAP) cnt = CAND_CAP;

  const float4* xv = (const float4*)(x + (size_t)b * H_DIM);
  for (int i = t; i < H_DIM / 4; i += 256) ((float4*)xr)[i] = xv[i];
  for (int i = t; i < cnt; i += 256) { cv[i] = cvals[b * CAND_CAP + i]; ci[i] = cidx[b * CAND_CAP + i]; }
  if (t == 0) { s_b32 = -1.0f; s_na = 0; s_nin = 0; }
  __syncthreads();

  bool tiny = (cnt < TOPK);                   // pathological: all candidates are in

  // rank (tie-break: equal value, lower slot counts as above) -> b32 = rank-31 value
  if (!tiny) {
    for (int i = t; i < cnt; i += 256) {
      float vi = cv[i]; int r = 0;
      for (int j = 0; j < cnt; ++j) { float vj = cv[j]; r += (vj > vi) || (vj == vi && j < i); }
      if (r == 31) s_b32 = vi;
    }
  }
  __syncthreads();
  float b32 = s_b32;

  // classify AMBIG
  if (!tiny) {
    for (int i = t; i < cnt; i += 256) {
      if (fabsf(cv[i] - b32) <= BAND) {
        unsigned int p = atomicAdd(&s_na, 1u);
        if (p < AMBIG_CAP) ai[p] = i;
      }
    }
  }
  __syncthreads();
  int na = (int)(s_na < AMBIG_CAP ? s_na : AMBIG_CAP);

  // fp64 rescore of AMBIG candidates (gather fp32 W_enc rows)
  int wv = t >> 6, lane = t & 63;
  for (int a = wv; a < na; a += 4) {
    int l = ci[ai[a]];
    const float4* wrow = (const float4*)(Wenc + (size_t)l * H_DIM);
    double acc = 0.0;
#pragma unroll
    for (int k8 = 0; k8 < 8; ++k8) {
      float4 ww = wrow[k8 * 64 + lane];
      float4 xx = ((const float4*)xr)[k8 * 64 + lane];
      acc += (double)ww.x * xx.x + (double)ww.y * xx.y + (double)ww.z * xx.z + (double)ww.w * xx.w;
    }
#pragma unroll
    for (int s = 32; s; s >>= 1) acc += __shfl_xor(acc, s, 64);
    if (lane == 0) ax[a] = acc;
  }
  __syncthreads();

  // emit SURE-IN (fp32-acc value; |err| <= 0.016 << 0.113 threshold)
  for (int i = t; i < cnt; i += 256) {
    float vi = cv[i];
    if (tiny || vi - b32 > BAND) {
      unsigned int p = atomicAdd(&s_nin, 1u);
      selv[b * TOPK + p] = vi; seli[b * TOPK + p] = ci[i];
      zout[(size_t)b * L_DIM + ci[i]] = vi;
    }
  }
  __syncthreads();
  int s0 = (int)s_nin;                        // <= 31 when !tiny; <= cnt < 32 when tiny

  // fill remaining 32-s0 slots from AMBIG by exact fp64 value (one wave, serial extract)
  if (t < 64) {
    int need = TOPK - s0; if (need < 0) need = 0;
    for (int k = 0; k < need; ++k) {
      double bv = -1.0e300; int bidx = 0x7fffffff; int bpos = -1;
      for (int a = lane; a < na; a += 64) {
        double v = ax[a]; int ii = ci[ai[a]];
        if (v > bv || (v == bv && ii < bidx)) { bv = v; bidx = ii; bpos = a; }
      }
#pragma unroll
      for (int sh = 32; sh; sh >>= 1) {
        double ov = __shfl_xor(bv, sh, 64);
        int oi = __shfl_xor(bidx, sh, 64);
        int op = __shfl_xor(bpos, sh, 64);
        if (ov > bv || (ov == bv && oi < bidx)) { bv = ov; bidx = oi; bpos = op; }
      }
      bool valid = (bpos >= 0) && (bv > -1.0e299);
      if (lane == 0) {
        selv[b * TOPK + s0 + k] = valid ? (float)bv : 0.0f;
        seli[b * TOPK + s0 + k] = valid ? bidx : 0;
        if (valid) zout[(size_t)b * L_DIM + bidx] = (float)bv;
      }
      for (int a = lane; a < na; a += 64) if (a == bpos) ax[a] = -1.0e300;
    }
  }
}

// ---------------------------------------------------------------- sparse decoder
__global__ __launch_bounds__(256) void k_decoder(const unsigned short* __restrict__ WdT,
                                                 const float* __restrict__ selv,
                                                 const int* __restrict__ seli,
                                                 float* __restrict__ xhat) {
  int b = blockIdx.x;
  int t = threadIdx.x;
  __shared__ float sv[TOPK];
  __shared__ int si[TOPK];
  if (t < TOPK) { sv[t] = selv[b * TOPK + t]; si[t] = seli[b * TOPK + t]; }
  __syncthreads();
  float acc[8] = {0.f, 0.f, 0.f, 0.f, 0.f, 0.f, 0.f, 0.f};
  for (int j = 0; j < TOPK; ++j) {
    float vj = sv[j];
    bf16x8 w = *(const bf16x8*)(WdT + (size_t)si[j] * H_DIM + t * 8);
#pragma unroll
    for (int i = 0; i < 8; ++i) acc[i] += vj * bf16_to_f32((unsigned short)w[i]);
  }
  float4 o0 = {acc[0], acc[1], acc[2], acc[3]};
  float4 o1 = {acc[4], acc[5], acc[6], acc[7]};
  float4* op = (float4*)(xhat + (size_t)b * H_DIM + t * 8);
  op[0] = o0; op[1] = o1;
}

extern "C" void kernel_launch(void* const* d_in, const int* in_sizes, int n_in,
                              void* d_out, int out_size, void* d_ws, size_t ws_size,
                              hipStream_t stream) {
  const float* x    = (const float*)d_in[0];
  const float* Wenc = (const float*)d_in[1];
  const float* Wdec = (const float*)d_in[2];
  // d_in[3] = topk (=32), hardcoded

  float* xhat = (float*)d_out;
  float* z    = (float*)d_out + (size_t)B_ROWS * H_DIM;

  char* ws = (char*)d_ws;
  if (ws_size < 168837120u) return;  // need ~161 MB scratch
  unsigned short* xbf    = (unsigned short*)(ws);                 // 16,777,216 B
  unsigned short* Wencbf = (unsigned short*)(ws + 16777216);      // 67,108,864 B
  unsigned short* WdT    = (unsigned short*)(ws + 83886080);      // 67,108,864 B
  int*    cidx  = (int*)  (ws + 150994944);                       //  8,388,608 B
  float*  cvals = (float*)(ws + 159383552);                       //  8,388,608 B
  int*    ccnt  = (int*)  (ws + 167772160);                       //     16,384 B
  float*  selv  = (float*)(ws + 167788544);                       //    524,288 B
  int*    seli  = (int*)  (ws + 168312832);                       //    524,288 B

  hipMemsetAsync(ccnt, 0, B_ROWS * sizeof(int), stream);
  k_convert<<<(2097152 + 255) / 256, 256, 0, stream>>>(x, xbf, 2097152);
  k_convert<<<(8388608 + 255) / 256, 256, 0, stream>>>(Wenc, Wencbf, 8388608);
  k_transpose<<<8192, 256, 0, stream>>>(Wdec, WdT);
  k_gemm<<<1024, 512, 0, stream>>>(xbf, Wencbf, cidx, cvals, ccnt);
  hipMemsetAsync(z, 0, (size_t)B_ROWS * L_DIM * sizeof(float), stream);
  k_fallback<<<B_ROWS, 256, 0, stream>>>(xbf, Wencbf, cidx, cvals, ccnt);
  k_topk<<<B_ROWS, 256, 0, stream>>>(x, Wenc, cidx, cvals, ccnt, z, selv, seli);
  k_decoder<<<B_ROWS, 256, 0, stream>>>(WdT, selv, seli, xhat);
}

// Round 6
// 662.280 us; speedup vs baseline: 1.4227x; 1.4227x over previous
//
#include <hip/hip_runtime.h>

#define B_ROWS 4096
#define H_DIM  2048
#define L_DIM  16384
#define TOPK   32
#define CAND_CAP 512
#define AMBIG_CAP 128
#define BAND 0.06f          // 2*e ; e = bf16-path max |v_bf - v_true| (est 0.018, margin 1.67x)

typedef __attribute__((ext_vector_type(8))) short bf16x8;
typedef __attribute__((ext_vector_type(4))) float f32x4;

__device__ __forceinline__ unsigned short f32_to_bf16(float f) {
  unsigned int u = __float_as_uint(f);
  u += 0x7FFFu + ((u >> 16) & 1u);           // round-to-nearest-even
  return (unsigned short)(u >> 16);
}
__device__ __forceinline__ float bf16_to_f32(unsigned short h) {
  return __uint_as_float(((unsigned int)h) << 16);
}

__device__ __forceinline__ void gload_lds16(const void* g, void* l) {
  __builtin_amdgcn_global_load_lds(
      (const __attribute__((address_space(1))) unsigned int*)g,
      (__attribute__((address_space(3))) unsigned int*)l, 16, 0, 0);
}

// ---------------------------------------------------------------- convert f32 -> bf16
__global__ __launch_bounds__(256) void k_convert(const float* __restrict__ src,
                                                 unsigned short* __restrict__ dst, int n4) {
  int i = blockIdx.x * 256 + threadIdx.x;
  if (i < n4) {
    float4 v = ((const float4*)src)[i];
    ushort4 o;
    o.x = f32_to_bf16(v.x); o.y = f32_to_bf16(v.y);
    o.z = f32_to_bf16(v.z); o.w = f32_to_bf16(v.w);
    ((ushort4*)dst)[i] = o;
  }
}

// ------------------------------------------- W_dec [H, L] f32  ->  WdT [L, H] bf16
__global__ __launch_bounds__(256) void k_transpose(const float* __restrict__ Wd,
                                                   unsigned short* __restrict__ WdT) {
  __shared__ float tile[64][65];              // [l_local][h_local], +1 pad
  int bi = blockIdx.x & 255;                  // l tile (16384/64 = 256)
  int bj = blockIdx.x >> 8;                   // h tile (2048/64 = 32)
  int t = threadIdx.x;
  int l0 = bi * 64, h0 = bj * 64;
#pragma unroll
  for (int p = 0; p < 4; ++p) {
    int hr = p * 16 + (t >> 4);
    int lc = (t & 15) * 4;
    float4 v = *(const float4*)(Wd + (size_t)(h0 + hr) * L_DIM + l0 + lc);
    tile[lc + 0][hr] = v.x; tile[lc + 1][hr] = v.y;
    tile[lc + 2][hr] = v.z; tile[lc + 3][hr] = v.w;
  }
  __syncthreads();
#pragma unroll
  for (int p = 0; p < 2; ++p) {
    int lr = p * 32 + (t >> 3);
    int hc = (t & 7) * 8;
    bf16x8 o;
#pragma unroll
    for (int i = 0; i < 8; ++i) o[i] = (short)f32_to_bf16(tile[lr][hc + i]);
    *(bf16x8*)(WdT + (size_t)(l0 + lr) * H_DIM + h0 + hc) = o;
  }
}

// ---------------------------------------------------------------- encoder GEMM (bf16 MFMA)
// R2-proven: 3-slot LDS ring, BK=32, counted vmcnt(4), XCD swizzle. Writes bf16 z_pre.
__global__ __launch_bounds__(512, 2) void k_gemm(const unsigned short* __restrict__ A,
                                                 const unsigned short* __restrict__ Bm,
                                                 unsigned short* __restrict__ Zp) {
  __shared__ unsigned short As[3 * 8192];     // 3 x 256x32 bf16 = 48 KB
  __shared__ unsigned short Bs[3 * 8192];     // 48 KB
  const size_t K = H_DIM;
  int bid = blockIdx.x;
  int cpx = gridDim.x >> 3;                   // 1024/8 = 128, bijective (nwg%8==0)
  int swz = (bid & 7) * cpx + (bid >> 3);
  int tm = swz >> 6;                          // 16 M-tiles (XCD-consecutive share A panel)
  int tn = swz & 63;                          // 64 N-tiles
  int t = threadIdx.x;
  int lane = t & 63;
  int w = t >> 6;
  int wm = w >> 2, wn = w & 3;                // 2 x 4 wave grid; per-wave 128x64

  int rloc = lane & 15;
  int kc = lane >> 4;                         // 0..3 : 8-elem K chunk
  int swzk = (kc ^ ((rloc >> 1) & 3)) << 3;   // bank swizzle (2-way max), shorts

  // staging decode: per thread row = j*128 + (t>>2), phys chunk (t&3) holds logical kcs
  int srow = t >> 2;
  int kcs = (t & 3) ^ ((srow >> 1) & 3);      // inverse-permuted global source (rule 21)
  const unsigned short* aS0 = A + (size_t)(tm * 256 + srow) * K + kcs * 8;
  const unsigned short* aS1 = aS0 + 128 * K;
  const unsigned short* bS0 = Bm + (size_t)(tn * 256 + srow) * K + kcs * 8;
  const unsigned short* bS1 = bS0 + 128 * K;
  int dA = t * 8;                             // linear LDS dest (shorts)

  f32x4 acc[8][4];
#pragma unroll
  for (int i = 0; i < 8; ++i)
#pragma unroll
    for (int j = 0; j < 4; ++j) { f32x4 z = {0.f, 0.f, 0.f, 0.f}; acc[i][j] = z; }

#define STAGE_A(kt, sw) { size_t ko = (size_t)(kt) * 32; \
    gload_lds16(aS0 + ko, &As[(sw) * 8192 + dA]); \
    gload_lds16(aS1 + ko, &As[(sw) * 8192 + 4096 + dA]); }
#define STAGE_B(kt, sw) { size_t ko = (size_t)(kt) * 32; \
    gload_lds16(bS0 + ko, &Bs[(sw) * 8192 + dA]); \
    gload_lds16(bS1 + ko, &Bs[(sw) * 8192 + 4096 + dA]); }

  // prologue: stage tile0 + tile1; wait tile0 (4 outstanding allowed)
  STAGE_A(0, 0) STAGE_B(0, 0)
  STAGE_A(1, 1) STAGE_B(1, 1)
  asm volatile("s_waitcnt vmcnt(4)" ::: "memory");
  __builtin_amdgcn_s_barrier();

  int sR = 0;
  const int aBase0 = (wm * 128 + rloc) * 32 + swzk;
  const int bBase0 = (wn * 64 + rloc) * 32 + swzk;
  const int NKT = H_DIM / 32;
  for (int kt = 0; kt < NKT; ++kt) {
    int sW = sR + 2; if (sW >= 3) sW -= 3;
    const unsigned short* Ab = &As[sR * 8192 + aBase0];
    const unsigned short* Bb = &Bs[sR * 8192 + bBase0];
    bool st = (kt + 2 < NKT);                 // wave-uniform
    // ---- phase 0: read A-half0 + all B frags; issue A-stage of tile kt+2
    bf16x8 a0[4], b0[4];
#pragma unroll
    for (int m = 0; m < 4; ++m) a0[m] = *(const bf16x8*)(Ab + m * 512);
#pragma unroll
    for (int n = 0; n < 4; ++n) b0[n] = *(const bf16x8*)(Bb + n * 512);
    if (st) STAGE_A(kt + 2, sW)
    __builtin_amdgcn_s_barrier();
    __builtin_amdgcn_s_setprio(1);
#pragma unroll
    for (int m = 0; m < 4; ++m)
#pragma unroll
      for (int n = 0; n < 4; ++n)
        acc[m][n] = __builtin_amdgcn_mfma_f32_16x16x32_bf16(a0[m], b0[n], acc[m][n], 0, 0, 0);
    __builtin_amdgcn_s_setprio(0);
    __builtin_amdgcn_s_barrier();
    // ---- phase 1: read A-half1 (B reused); issue B-stage of tile kt+2
    bf16x8 a1[4];
#pragma unroll
    for (int m = 0; m < 4; ++m) a1[m] = *(const bf16x8*)(Ab + (m + 4) * 512);
    if (st) STAGE_B(kt + 2, sW)
    __builtin_amdgcn_s_barrier();
    __builtin_amdgcn_s_setprio(1);
#pragma unroll
    for (int m = 0; m < 4; ++m)
#pragma unroll
      for (int n = 0; n < 4; ++n)
        acc[m + 4][n] = __builtin_amdgcn_mfma_f32_16x16x32_bf16(a1[m], b0[n], acc[m + 4][n], 0, 0, 0);
    __builtin_amdgcn_s_setprio(0);
    // ---- tile boundary: counted wait
    if (kt < NKT - 2) { asm volatile("s_waitcnt vmcnt(4)" ::: "memory"); }
    else if (kt == NKT - 2) { asm volatile("s_waitcnt vmcnt(0)" ::: "memory"); }
    __builtin_amdgcn_s_barrier();
    ++sR; if (sR == 3) sR = 0;
  }
#undef STAGE_A
#undef STAGE_B
  // epilogue: C/D layout col=lane&15, row=(lane>>4)*4+reg [m89]; relu + bf16
  int colg = lane & 15, quad = lane >> 4;
  size_t rbase = (size_t)(tm * 256 + wm * 128 + quad * 4);
  int cbase = tn * 256 + wn * 64 + colg;
#pragma unroll
  for (int m = 0; m < 8; ++m)
#pragma unroll
    for (int n = 0; n < 4; ++n) {
      size_t rr = rbase + m * 16;
      int cc = cbase + n * 16;
#pragma unroll
      for (int r = 0; r < 4; ++r)
        Zp[(rr + r) * L_DIM + cc] = f32_to_bf16(fmaxf(acc[m][n][r], 0.0f));
    }
}

// ------------------------------------- single-pass candidate collect (fixed threshold)
// Block-LOCAL atomics only (R5 lesson: global ccnt atomics from gemm = cross-XCD disaster).
// v32 ~ N(2.89, 0.058) over rows -> thr 2.3 is ~10 sigma safe; ~175 cands/row expected.
__global__ __launch_bounds__(256) void k_collect(const unsigned short* __restrict__ zp,
                                                 int* __restrict__ cidx,
                                                 float* __restrict__ cvals,
                                                 int* __restrict__ ccnt) {
  int b = blockIdx.x;
  const bf16x8* row = (const bf16x8*)(zp + (size_t)b * L_DIM);
  __shared__ unsigned int s_cnt;
  int t = threadIdx.x;
  float thr = 2.3f;
  for (int attempt = 0; attempt < 8; ++attempt) {
    if (t == 0) s_cnt = 0;
    __syncthreads();
    for (int i = t; i < L_DIM / 8; i += 256) {
      bf16x8 v = row[i];
#pragma unroll
      for (int q = 0; q < 8; ++q) {
        float f = bf16_to_f32((unsigned short)v[q]);
        if (f > thr) {
          unsigned int p = atomicAdd(&s_cnt, 1u);
          if (p < CAND_CAP) { cidx[b * CAND_CAP + p] = i * 8 + q; cvals[b * CAND_CAP + p] = f; }
        }
      }
    }
    __syncthreads();
    if (s_cnt >= 40 || thr <= 0.0f) break;
    thr -= 0.6f; if (thr < 0.0f) thr = 0.0f;
    __syncthreads();
  }
  if (t == 0) ccnt[b] = (int)(s_cnt < CAND_CAP ? s_cnt : CAND_CAP);
}

// ----------------- fused topk: zero-fill z row -> rank -> classify vs b32 ->
//                   fp64-rescore AMBIG only -> emit final 32 (scatter z + selv/seli)
// SURE-IN  (v_bf > b32+BAND): provably in true top-32 given |v_bf-v_true| <= BAND/2.
// SURE-OUT (v_bf < b32-BAND): provably out. AMBIG band (~5/row) rescored in fp64.
__global__ __launch_bounds__(256) void k_topk(const float* __restrict__ x,
                                              const float* __restrict__ Wenc,
                                              const int* __restrict__ cidx,
                                              const float* __restrict__ cvals,
                                              const int* __restrict__ ccnt,
                                              float* __restrict__ zout,
                                              float* __restrict__ selv,
                                              int* __restrict__ seli) {
  int b = blockIdx.x;
  int t = threadIdx.x;
  __shared__ float xr[H_DIM];                 // 8 KB
  __shared__ float cv[CAND_CAP];
  __shared__ int   ci[CAND_CAP];
  __shared__ float s_b32;
  __shared__ unsigned int s_na, s_nin;
  __shared__ int    ai[AMBIG_CAP];
  __shared__ double ax[AMBIG_CAP];
  int cnt = ccnt[b]; if (cnt > CAND_CAP) cnt = CAND_CAP;

  const float4* xv = (const float4*)(x + (size_t)b * H_DIM);
  for (int i = t; i < H_DIM / 4; i += 256) ((float4*)xr)[i] = xv[i];
  for (int i = t; i < cnt; i += 256) { cv[i] = cvals[b * CAND_CAP + i]; ci[i] = cidx[b * CAND_CAP + i]; }
  if (t == 0) { s_b32 = -1.0f; s_na = 0; s_nin = 0; }
  // zero-fill this block's z row (replaces global memset; zpre already consumed by k_collect)
  {
    float4 zz = {0.f, 0.f, 0.f, 0.f};
    float4* zrow = (float4*)(zout + (size_t)b * L_DIM);
#pragma unroll
    for (int i = 0; i < L_DIM / 4 / 256; ++i) zrow[i * 256 + t] = zz;
  }
  __syncthreads();

  bool tiny = (cnt < TOPK);                   // pathological: all candidates are in

  // rank (tie-break: equal value, lower slot counts as above) -> b32 = rank-31 value
  if (!tiny) {
    for (int i = t; i < cnt; i += 256) {
      float vi = cv[i]; int r = 0;
      for (int j = 0; j < cnt; ++j) { float vj = cv[j]; r += (vj > vi) || (vj == vi && j < i); }
      if (r == 31) s_b32 = vi;
    }
  }
  __syncthreads();
  float b32 = s_b32;

  // classify AMBIG
  if (!tiny) {
    for (int i = t; i < cnt; i += 256) {
      if (fabsf(cv[i] - b32) <= BAND) {
        unsigned int p = atomicAdd(&s_na, 1u);
        if (p < AMBIG_CAP) ai[p] = i;
      }
    }
  }
  __syncthreads();
  int na = (int)(s_na < AMBIG_CAP ? s_na : AMBIG_CAP);

  // fp64 rescore of AMBIG candidates (gather fp32 W_enc rows)
  int wv = t >> 6, lane = t & 63;
  for (int a = wv; a < na; a += 4) {
    int l = ci[ai[a]];
    const float4* wrow = (const float4*)(Wenc + (size_t)l * H_DIM);
    double acc = 0.0;
#pragma unroll
    for (int k8 = 0; k8 < 8; ++k8) {
      float4 ww = wrow[k8 * 64 + lane];
      float4 xx = ((const float4*)xr)[k8 * 64 + lane];
      acc += (double)ww.x * xx.x + (double)ww.y * xx.y + (double)ww.z * xx.z + (double)ww.w * xx.w;
    }
#pragma unroll
    for (int s = 32; s; s >>= 1) acc += __shfl_xor(acc, s, 64);
    if (lane == 0) ax[a] = acc;
  }
  __syncthreads();

  // emit SURE-IN (bf16-path value; |err| <= 0.03 << 0.113 threshold)
  for (int i = t; i < cnt; i += 256) {
    float vi = cv[i];
    if (tiny || vi - b32 > BAND) {
      unsigned int p = atomicAdd(&s_nin, 1u);
      selv[b * TOPK + p] = vi; seli[b * TOPK + p] = ci[i];
      zout[(size_t)b * L_DIM + ci[i]] = vi;
    }
  }
  __syncthreads();
  int s0 = (int)s_nin;                        // <= 31 when !tiny; <= cnt < 32 when tiny

  // fill remaining 32-s0 slots from AMBIG by exact fp64 value (one wave, serial extract)
  if (t < 64) {
    int need = TOPK - s0; if (need < 0) need = 0;
    for (int k = 0; k < need; ++k) {
      double bv = -1.0e300; int bidx = 0x7fffffff; int bpos = -1;
      for (int a = lane; a < na; a += 64) {
        double v = ax[a]; int ii = ci[ai[a]];
        if (v > bv || (v == bv && ii < bidx)) { bv = v; bidx = ii; bpos = a; }
      }
#pragma unroll
      for (int sh = 32; sh; sh >>= 1) {
        double ov = __shfl_xor(bv, sh, 64);
        int oi = __shfl_xor(bidx, sh, 64);
        int op = __shfl_xor(bpos, sh, 64);
        if (ov > bv || (ov == bv && oi < bidx)) { bv = ov; bidx = oi; bpos = op; }
      }
      bool valid = (bpos >= 0) && (bv > -1.0e299);
      if (lane == 0) {
        selv[b * TOPK + s0 + k] = valid ? (float)bv : 0.0f;
        seli[b * TOPK + s0 + k] = valid ? bidx : 0;
        if (valid) zout[(size_t)b * L_DIM + bidx] = (float)bv;
      }
      for (int a = lane; a < na; a += 64) if (a == bpos) ax[a] = -1.0e300;
    }
  }
}

// ---------------------------------------------------------------- sparse decoder
__global__ __launch_bounds__(256) void k_decoder(const unsigned short* __restrict__ WdT,
                                                 const float* __restrict__ selv,
                                                 const int* __restrict__ seli,
                                                 float* __restrict__ xhat) {
  int b = blockIdx.x;
  int t = threadIdx.x;
  __shared__ float sv[TOPK];
  __shared__ int si[TOPK];
  if (t < TOPK) { sv[t] = selv[b * TOPK + t]; si[t] = seli[b * TOPK + t]; }
  __syncthreads();
  float acc[8] = {0.f, 0.f, 0.f, 0.f, 0.f, 0.f, 0.f, 0.f};
  for (int j = 0; j < TOPK; ++j) {
    float vj = sv[j];
    bf16x8 w = *(const bf16x8*)(WdT + (size_t)si[j] * H_DIM + t * 8);
#pragma unroll
    for (int i = 0; i < 8; ++i) acc[i] += vj * bf16_to_f32((unsigned short)w[i]);
  }
  float4 o0 = {acc[0], acc[1], acc[2], acc[3]};
  float4 o1 = {acc[4], acc[5], acc[6], acc[7]};
  float4* op = (float4*)(xhat + (size_t)b * H_DIM + t * 8);
  op[0] = o0; op[1] = o1;
}

extern "C" void kernel_launch(void* const* d_in, const int* in_sizes, int n_in,
                              void* d_out, int out_size, void* d_ws, size_t ws_size,
                              hipStream_t stream) {
  const float* x    = (const float*)d_in[0];
  const float* Wenc = (const float*)d_in[1];
  const float* Wdec = (const float*)d_in[2];
  // d_in[3] = topk (=32), hardcoded

  float* xhat = (float*)d_out;
  float* z    = (float*)d_out + (size_t)B_ROWS * H_DIM;

  char* ws = (char*)d_ws;
  if (ws_size < 168837120u) return;  // need ~161 MB scratch
  unsigned short* xbf    = (unsigned short*)(ws);                 // 16,777,216 B
  unsigned short* Wencbf = (unsigned short*)(ws + 16777216);      // 67,108,864 B
  unsigned short* WdT    = (unsigned short*)(ws + 83886080);      // 67,108,864 B
  int*    cidx  = (int*)  (ws + 150994944);                       //  8,388,608 B
  float*  cvals = (float*)(ws + 159383552);                       //  8,388,608 B
  int*    ccnt  = (int*)  (ws + 167772160);                       //     16,384 B
  float*  selv  = (float*)(ws + 167788544);                       //    524,288 B
  int*    seli  = (int*)  (ws + 168312832);                       //    524,288 B

  unsigned short* zpre = (unsigned short*)z;                      // bf16 scratch in z region

  k_convert<<<(2097152 + 255) / 256, 256, 0, stream>>>(x, xbf, 2097152);
  k_convert<<<(8388608 + 255) / 256, 256, 0, stream>>>(Wenc, Wencbf, 8388608);
  k_transpose<<<8192, 256, 0, stream>>>(Wdec, WdT);
  k_gemm<<<1024, 512, 0, stream>>>(xbf, Wencbf, zpre);            // bf16 relu'd z_pre
  k_collect<<<B_ROWS, 256, 0, stream>>>(zpre, cidx, cvals, ccnt);
  k_topk<<<B_ROWS, 256, 0, stream>>>(x, Wenc, cidx, cvals, ccnt, z, selv, seli);
  k_decoder<<<B_ROWS, 256, 0, stream>>>(WdT, selv, seli, xhat);
}

// Round 9
// 640.996 us; speedup vs baseline: 1.4699x; 1.0332x over previous
//
#include <hip/hip_runtime.h>

#define B_ROWS 4096
#define H_DIM  2048
#define L_DIM  16384
#define TOPK   32
#define CAND_CAP 512
#define AMBIG_CAP 128
#define BAND 0.06f          // 2*e ; e = bf16-path max |v_bf - v_true| (est 0.018, margin 1.67x)
#define ZP_STRIDE (2 * L_DIM)  // bf16 zpre row stride in shorts: row b lives INSIDE fp32 z row b

typedef __attribute__((ext_vector_type(8))) short bf16x8;
typedef __attribute__((ext_vector_type(4))) float f32x4;

__device__ __forceinline__ unsigned short f32_to_bf16(float f) {
  unsigned int u = __float_as_uint(f);
  u += 0x7FFFu + ((u >> 16) & 1u);           // round-to-nearest-even
  return (unsigned short)(u >> 16);
}
__device__ __forceinline__ float bf16_to_f32(unsigned short h) {
  return __uint_as_float(((unsigned int)h) << 16);
}

__device__ __forceinline__ void gload_lds16(const void* g, void* l) {
  __builtin_amdgcn_global_load_lds(
      (const __attribute__((address_space(1))) unsigned int*)g,
      (__attribute__((address_space(3))) unsigned int*)l, 16, 0, 0);
}

// ---------------------------------------------------------------- convert f32 -> bf16
__global__ __launch_bounds__(256) void k_convert(const float* __restrict__ src,
                                                 unsigned short* __restrict__ dst, int n4) {
  int i = blockIdx.x * 256 + threadIdx.x;
  if (i < n4) {
    float4 v = ((const float4*)src)[i];
    ushort4 o;
    o.x = f32_to_bf16(v.x); o.y = f32_to_bf16(v.y);
    o.z = f32_to_bf16(v.z); o.w = f32_to_bf16(v.w);
    ((ushort4*)dst)[i] = o;
  }
}

// ------------------------------------------- W_dec [H, L] f32  ->  WdT [L, H] bf16
__global__ __launch_bounds__(256) void k_transpose(const float* __restrict__ Wd,
                                                   unsigned short* __restrict__ WdT) {
  __shared__ float tile[64][65];              // [l_local][h_local], +1 pad
  int bi = blockIdx.x & 255;                  // l tile (16384/64 = 256)
  int bj = blockIdx.x >> 8;                   // h tile (2048/64 = 32)
  int t = threadIdx.x;
  int l0 = bi * 64, h0 = bj * 64;
#pragma unroll
  for (int p = 0; p < 4; ++p) {
    int hr = p * 16 + (t >> 4);
    int lc = (t & 15) * 4;
    float4 v = *(const float4*)(Wd + (size_t)(h0 + hr) * L_DIM + l0 + lc);
    tile[lc + 0][hr] = v.x; tile[lc + 1][hr] = v.y;
    tile[lc + 2][hr] = v.z; tile[lc + 3][hr] = v.w;
  }
  __syncthreads();
#pragma unroll
  for (int p = 0; p < 2; ++p) {
    int lr = p * 32 + (t >> 3);
    int hc = (t & 7) * 8;
    bf16x8 o;
#pragma unroll
    for (int i = 0; i < 8; ++i) o[i] = (short)f32_to_bf16(tile[lr][hc + i]);
    *(bf16x8*)(WdT + (size_t)(l0 + lr) * H_DIM + h0 + hc) = o;
  }
}

// ---------------------------------------------------------------- encoder GEMM (bf16 MFMA)
// R2/R6-proven: 3-slot LDS ring, BK=32, counted vmcnt(4), XCD swizzle.
// Writes bf16 z_pre at ZP_STRIDE so row b aliases ONLY fp32 z row b (block-local in k_finish).
__global__ __launch_bounds__(512, 2) void k_gemm(const unsigned short* __restrict__ A,
                                                 const unsigned short* __restrict__ Bm,
                                                 unsigned short* __restrict__ Zp) {
  __shared__ unsigned short As[3 * 8192];     // 3 x 256x32 bf16 = 48 KB
  __shared__ unsigned short Bs[3 * 8192];     // 48 KB
  const size_t K = H_DIM;
  int bid = blockIdx.x;
  int cpx = gridDim.x >> 3;                   // 1024/8 = 128, bijective (nwg%8==0)
  int swz = (bid & 7) * cpx + (bid >> 3);
  int tm = swz >> 6;                          // 16 M-tiles (XCD-consecutive share A panel)
  int tn = swz & 63;                          // 64 N-tiles
  int t = threadIdx.x;
  int lane = t & 63;
  int w = t >> 6;
  int wm = w >> 2, wn = w & 3;                // 2 x 4 wave grid; per-wave 128x64

  int rloc = lane & 15;
  int kc = lane >> 4;                         // 0..3 : 8-elem K chunk
  int swzk = (kc ^ ((rloc >> 1) & 3)) << 3;   // bank swizzle (2-way max), shorts

  // staging decode: per thread row = j*128 + (t>>2), phys chunk (t&3) holds logical kcs
  int srow = t >> 2;
  int kcs = (t & 3) ^ ((srow >> 1) & 3);      // inverse-permuted global source (rule 21)
  const unsigned short* aS0 = A + (size_t)(tm * 256 + srow) * K + kcs * 8;
  const unsigned short* aS1 = aS0 + 128 * K;
  const unsigned short* bS0 = Bm + (size_t)(tn * 256 + srow) * K + kcs * 8;
  const unsigned short* bS1 = bS0 + 128 * K;
  int dA = t * 8;                             // linear LDS dest (shorts)

  f32x4 acc[8][4];
#pragma unroll
  for (int i = 0; i < 8; ++i)
#pragma unroll
    for (int j = 0; j < 4; ++j) { f32x4 z = {0.f, 0.f, 0.f, 0.f}; acc[i][j] = z; }

#define STAGE_A(kt, sw) { size_t ko = (size_t)(kt) * 32; \
    gload_lds16(aS0 + ko, &As[(sw) * 8192 + dA]); \
    gload_lds16(aS1 + ko, &As[(sw) * 8192 + 4096 + dA]); }
#define STAGE_B(kt, sw) { size_t ko = (size_t)(kt) * 32; \
    gload_lds16(bS0 + ko, &Bs[(sw) * 8192 + dA]); \
    gload_lds16(bS1 + ko, &Bs[(sw) * 8192 + 4096 + dA]); }

  // prologue: stage tile0 + tile1; wait tile0 (4 outstanding allowed)
  STAGE_A(0, 0) STAGE_B(0, 0)
  STAGE_A(1, 1) STAGE_B(1, 1)
  asm volatile("s_waitcnt vmcnt(4)" ::: "memory");
  __builtin_amdgcn_s_barrier();

  int sR = 0;
  const int aBase0 = (wm * 128 + rloc) * 32 + swzk;
  const int bBase0 = (wn * 64 + rloc) * 32 + swzk;
  const int NKT = H_DIM / 32;
  for (int kt = 0; kt < NKT; ++kt) {
    int sW = sR + 2; if (sW >= 3) sW -= 3;
    const unsigned short* Ab = &As[sR * 8192 + aBase0];
    const unsigned short* Bb = &Bs[sR * 8192 + bBase0];
    bool st = (kt + 2 < NKT);                 // wave-uniform
    // ---- phase 0: read A-half0 + all B frags; issue A-stage of tile kt+2
    bf16x8 a0[4], b0[4];
#pragma unroll
    for (int m = 0; m < 4; ++m) a0[m] = *(const bf16x8*)(Ab + m * 512);
#pragma unroll
    for (int n = 0; n < 4; ++n) b0[n] = *(const bf16x8*)(Bb + n * 512);
    if (st) STAGE_A(kt + 2, sW)
    __builtin_amdgcn_s_barrier();
    __builtin_amdgcn_s_setprio(1);
#pragma unroll
    for (int m = 0; m < 4; ++m)
#pragma unroll
      for (int n = 0; n < 4; ++n)
        acc[m][n] = __builtin_amdgcn_mfma_f32_16x16x32_bf16(a0[m], b0[n], acc[m][n], 0, 0, 0);
    __builtin_amdgcn_s_setprio(0);
    __builtin_amdgcn_s_barrier();
    // ---- phase 1: read A-half1 (B reused); issue B-stage of tile kt+2
    bf16x8 a1[4];
#pragma unroll
    for (int m = 0; m < 4; ++m) a1[m] = *(const bf16x8*)(Ab + (m + 4) * 512);
    if (st) STAGE_B(kt + 2, sW)
    __builtin_amdgcn_s_barrier();
    __builtin_amdgcn_s_setprio(1);
#pragma unroll
    for (int m = 0; m < 4; ++m)
#pragma unroll
      for (int n = 0; n < 4; ++n)
        acc[m + 4][n] = __builtin_amdgcn_mfma_f32_16x16x32_bf16(a1[m], b0[n], acc[m + 4][n], 0, 0, 0);
    __builtin_amdgcn_s_setprio(0);
    // ---- tile boundary: counted wait
    if (kt < NKT - 2) { asm volatile("s_waitcnt vmcnt(4)" ::: "memory"); }
    else if (kt == NKT - 2) { asm volatile("s_waitcnt vmcnt(0)" ::: "memory"); }
    __builtin_amdgcn_s_barrier();
    ++sR; if (sR == 3) sR = 0;
  }
#undef STAGE_A
#undef STAGE_B
  // epilogue: C/D layout col=lane&15, row=(lane>>4)*4+reg [m89]; relu + bf16; stride 2L
  int colg = lane & 15, quad = lane >> 4;
  size_t rbase = (size_t)(tm * 256 + wm * 128 + quad * 4);
  int cbase = tn * 256 + wn * 64 + colg;
#pragma unroll
  for (int m = 0; m < 8; ++m)
#pragma unroll
    for (int n = 0; n < 4; ++n) {
      size_t rr = rbase + m * 16;
      int cc = cbase + n * 16;
#pragma unroll
      for (int r = 0; r < 4; ++r)
        Zp[(rr + r) * ZP_STRIDE + cc] = f32_to_bf16(fmaxf(acc[m][n][r], 0.0f));
    }
}

// ---------------- fused tail: collect (block-local) -> zero z row -> rank -> classify ->
//                  fp64-rescore AMBIG -> scatter z + LDS sel -> decode -> x_hat
// zpre row b lives in the first 32KB of fp32 z row b (ZP_STRIDE) -> all traffic block-local.
__global__ __launch_bounds__(256) void k_finish(const float* __restrict__ x,
                                                const float* __restrict__ Wenc,
                                                const unsigned short* __restrict__ WdT,
                                                float* __restrict__ zout,
                                                float* __restrict__ xhat) {
  int b = blockIdx.x;
  int t = threadIdx.x;
  __shared__ float xr[H_DIM];                 // 8 KB
  __shared__ float cv[CAND_CAP];
  __shared__ int   ci[CAND_CAP];
  __shared__ float s_b32;
  __shared__ unsigned int s_cnt, s_na, s_nin;
  __shared__ int    ai[AMBIG_CAP];
  __shared__ double ax[AMBIG_CAP];
  __shared__ float  sv[TOPK];
  __shared__ int    si[TOPK];

  const bf16x8* row = (const bf16x8*)((const unsigned short*)zout + (size_t)b * ZP_STRIDE);
  const float4* xv = (const float4*)(x + (size_t)b * H_DIM);
  for (int i = t; i < H_DIM / 4; i += 256) ((float4*)xr)[i] = xv[i];

  // collect with retry (block-local atomics only — R5 lesson)
  float thr = 2.3f;                           // v32 ~ N(2.89, 0.058) -> ~10 sigma safe
  for (int attempt = 0; attempt < 8; ++attempt) {
    if (t == 0) s_cnt = 0;
    __syncthreads();
    for (int i = t; i < L_DIM / 8; i += 256) {
      bf16x8 v = row[i];
#pragma unroll
      for (int q = 0; q < 8; ++q) {
        float f = bf16_to_f32((unsigned short)v[q]);
        if (f > thr) {
          unsigned int p = atomicAdd(&s_cnt, 1u);
          if (p < CAND_CAP) { ci[p] = i * 8 + q; cv[p] = f; }
        }
      }
    }
    __syncthreads();
    if (s_cnt >= 40 || thr <= 0.0f) break;
    thr -= 0.6f; if (thr < 0.0f) thr = 0.0f;
    __syncthreads();
  }
  int cnt = (int)(s_cnt < CAND_CAP ? s_cnt : CAND_CAP);

  // zero this block's z row (this block's zpre copy fully consumed above)
  __syncthreads();
  {
    float4 zz = {0.f, 0.f, 0.f, 0.f};
    float4* zr = (float4*)(zout + (size_t)b * L_DIM);
#pragma unroll
    for (int i = 0; i < L_DIM / 4 / 256; ++i) zr[i * 256 + t] = zz;
  }
  if (t == 0) { s_b32 = -1.0f; s_na = 0; s_nin = 0; }
  __syncthreads();

  bool tiny = (cnt < TOPK);                   // pathological: all candidates are in

  // rank (tie-break: equal value, lower slot counts as above) -> b32 = rank-31 value
  if (!tiny) {
    for (int i = t; i < cnt; i += 256) {
      float vi = cv[i]; int r = 0;
      for (int j = 0; j < cnt; ++j) { float vj = cv[j]; r += (vj > vi) || (vj == vi && j < i); }
      if (r == 31) s_b32 = vi;
    }
  }
  __syncthreads();
  float b32 = s_b32;

  // classify AMBIG
  if (!tiny) {
    for (int i = t; i < cnt; i += 256) {
      if (fabsf(cv[i] - b32) <= BAND) {
        unsigned int p = atomicAdd(&s_na, 1u);
        if (p < AMBIG_CAP) ai[p] = i;
      }
    }
  }
  __syncthreads();
  int na = (int)(s_na < AMBIG_CAP ? s_na : AMBIG_CAP);

  // fp64 rescore of AMBIG candidates (gather fp32 W_enc rows)
  int wv = t >> 6, lane = t & 63;
  for (int a = wv; a < na; a += 4) {
    int l = ci[ai[a]];
    const float4* wrow = (const float4*)(Wenc + (size_t)l * H_DIM);
    double acc = 0.0;
#pragma unroll
    for (int k8 = 0; k8 < 8; ++k8) {
      float4 ww = wrow[k8 * 64 + lane];
      float4 xx = ((const float4*)xr)[k8 * 64 + lane];
      acc += (double)ww.x * xx.x + (double)ww.y * xx.y + (double)ww.z * xx.z + (double)ww.w * xx.w;
    }
#pragma unroll
    for (int s = 32; s; s >>= 1) acc += __shfl_xor(acc, s, 64);
    if (lane == 0) ax[a] = acc;
  }
  __syncthreads();

  // emit SURE-IN (bf16-path value; |err| <= 0.03 << 0.113 threshold)
  for (int i = t; i < cnt; i += 256) {
    float vi = cv[i];
    if (tiny || vi - b32 > BAND) {
      unsigned int p = atomicAdd(&s_nin, 1u);
      sv[p] = vi; si[p] = ci[i];
      zout[(size_t)b * L_DIM + ci[i]] = vi;
    }
  }
  __syncthreads();
  int s0 = (int)s_nin;                        // <= 31 when !tiny; <= cnt < 32 when tiny

  // fill remaining 32-s0 slots from AMBIG by exact fp64 value (one wave, serial extract)
  if (t < 64) {
    int need = TOPK - s0; if (need < 0) need = 0;
    for (int k = 0; k < need; ++k) {
      double bv = -1.0e300; int bidx = 0x7fffffff; int bpos = -1;
      for (int a = lane; a < na; a += 64) {
        double v = ax[a]; int ii = ci[ai[a]];
        if (v > bv || (v == bv && ii < bidx)) { bv = v; bidx = ii; bpos = a; }
      }
#pragma unroll
      for (int sh = 32; sh; sh >>= 1) {
        double ov = __shfl_xor(bv, sh, 64);
        int oi = __shfl_xor(bidx, sh, 64);
        int op = __shfl_xor(bpos, sh, 64);
        if (ov > bv || (ov == bv && oi < bidx)) { bv = ov; bidx = oi; bpos = op; }
      }
      bool valid = (bpos >= 0) && (bv > -1.0e299);
      if (lane == 0) {
        sv[s0 + k] = valid ? (float)bv : 0.0f;
        si[s0 + k] = valid ? bidx : 0;
        if (valid) zout[(size_t)b * L_DIM + bidx] = (float)bv;
      }
      for (int a = lane; a < na; a += 64) if (a == bpos) ax[a] = -1.0e300;
    }
  }
  __syncthreads();

  // decode: x_hat row = sum_j sv[j] * WdT[si[j], :]
  float acc[8] = {0.f, 0.f, 0.f, 0.f, 0.f, 0.f, 0.f, 0.f};
  for (int j = 0; j < TOPK; ++j) {
    float vj = sv[j];
    bf16x8 ww = *(const bf16x8*)(WdT + (size_t)si[j] * H_DIM + t * 8);
#pragma unroll
    for (int i = 0; i < 8; ++i) acc[i] += vj * bf16_to_f32((unsigned short)ww[i]);
  }
  float4 o0 = {acc[0], acc[1], acc[2], acc[3]};
  float4 o1 = {acc[4], acc[5], acc[6], acc[7]};
  float4* op = (float4*)(xhat + (size_t)b * H_DIM + t * 8);
  op[0] = o0; op[1] = o1;
}

extern "C" void kernel_launch(void* const* d_in, const int* in_sizes, int n_in,
                              void* d_out, int out_size, void* d_ws, size_t ws_size,
                              hipStream_t stream) {
  const float* x    = (const float*)d_in[0];
  const float* Wenc = (const float*)d_in[1];
  const float* Wdec = (const float*)d_in[2];
  // d_in[3] = topk (=32), hardcoded

  float* xhat = (float*)d_out;
  float* z    = (float*)d_out + (size_t)B_ROWS * H_DIM;

  char* ws = (char*)d_ws;
  if (ws_size < 150994944u) return;  // need 144 MB scratch
  unsigned short* xbf    = (unsigned short*)(ws);                 // 16,777,216 B
  unsigned short* Wencbf = (unsigned short*)(ws + 16777216);      // 67,108,864 B
  unsigned short* WdT    = (unsigned short*)(ws + 83886080);      // 67,108,864 B

  unsigned short* zpre = (unsigned short*)z;                      // bf16, stride ZP_STRIDE

  k_convert<<<(2097152 + 255) / 256, 256, 0, stream>>>(x, xbf, 2097152);
  k_convert<<<(8388608 + 255) / 256, 256, 0, stream>>>(Wenc, Wencbf, 8388608);
  k_transpose<<<8192, 256, 0, stream>>>(Wdec, WdT);
  k_gemm<<<1024, 512, 0, stream>>>(xbf, Wencbf, zpre);            // bf16 relu'd z_pre
  k_finish<<<B_ROWS, 256, 0, stream>>>(x, Wenc, WdT, z, xhat);
}

// Round 10
// 580.095 us; speedup vs baseline: 1.6242x; 1.1050x over previous
//
#include <hip/hip_runtime.h>

#define B_ROWS 4096
#define H_DIM  2048
#define L_DIM  16384
#define TOPK   32
#define CAND_CAP 512
#define AMBIG_CAP 128
#define BAND 0.06f          // 2*e ; e = bf16-path max |v_bf - v_true| (est 0.018, margin 1.67x)
#define ZP_STRIDE (2 * L_DIM)  // bf16 zpre row stride in shorts: row b lives INSIDE fp32 z row b
#define NKT 32              // K-tiles of 64: 2048/64

typedef __attribute__((ext_vector_type(8))) short bf16x8;
typedef __attribute__((ext_vector_type(4))) float f32x4;

__device__ __forceinline__ unsigned short f32_to_bf16(float f) {
  unsigned int u = __float_as_uint(f);
  u += 0x7FFFu + ((u >> 16) & 1u);           // round-to-nearest-even
  return (unsigned short)(u >> 16);
}
__device__ __forceinline__ float bf16_to_f32(unsigned short h) {
  return __uint_as_float(((unsigned int)h) << 16);
}

__device__ __forceinline__ void gload_lds16(const void* g, void* l) {
  __builtin_amdgcn_global_load_lds(
      (const __attribute__((address_space(1))) unsigned int*)g,
      (__attribute__((address_space(3))) unsigned int*)l, 16, 0, 0);
}

// ---------------------------------------------------------------- convert f32 -> bf16
__global__ __launch_bounds__(256) void k_convert(const float* __restrict__ src,
                                                 unsigned short* __restrict__ dst, int n4) {
  int i = blockIdx.x * 256 + threadIdx.x;
  if (i < n4) {
    float4 v = ((const float4*)src)[i];
    ushort4 o;
    o.x = f32_to_bf16(v.x); o.y = f32_to_bf16(v.y);
    o.z = f32_to_bf16(v.z); o.w = f32_to_bf16(v.w);
    ((ushort4*)dst)[i] = o;
  }
}

// ------------------------------------------- W_dec [H, L] f32  ->  WdT [L, H] bf16
__global__ __launch_bounds__(256) void k_transpose(const float* __restrict__ Wd,
                                                   unsigned short* __restrict__ WdT) {
  __shared__ float tile[64][65];              // [l_local][h_local], +1 pad
  int bi = blockIdx.x & 255;                  // l tile (16384/64 = 256)
  int bj = blockIdx.x >> 8;                   // h tile (2048/64 = 32)
  int t = threadIdx.x;
  int l0 = bi * 64, h0 = bj * 64;
#pragma unroll
  for (int p = 0; p < 4; ++p) {
    int hr = p * 16 + (t >> 4);
    int lc = (t & 15) * 4;
    float4 v = *(const float4*)(Wd + (size_t)(h0 + hr) * L_DIM + l0 + lc);
    tile[lc + 0][hr] = v.x; tile[lc + 1][hr] = v.y;
    tile[lc + 2][hr] = v.z; tile[lc + 3][hr] = v.w;
  }
  __syncthreads();
#pragma unroll
  for (int p = 0; p < 2; ++p) {
    int lr = p * 32 + (t >> 3);
    int hc = (t & 7) * 8;
    bf16x8 o;
#pragma unroll
    for (int i = 0; i < 8; ++i) o[i] = (short)f32_to_bf16(tile[lr][hc + i]);
    *(bf16x8*)(WdT + (size_t)(l0 + lr) * H_DIM + h0 + hc) = o;
  }
}

// ---------------------------------------------------------------- encoder GEMM (bf16 MFMA)
// m201-style: 256x256 tile, BK=64, 2-dbuf (128 KiB LDS), 4 C-quadrant phases/K-tile
// (ds_reads 12/4/8/0; B quadrants held in regs), 1 half-tile stage unit (2 gloads)/phase:
//   P0: A(t+1,h0)->buf^1   P1: A(t+1,h1)->buf^1   P2: B(t+2,h0)->buf   P3: B(t+2,h1)->buf
// One counted vmcnt(4)/tile (never 0 until peeled tail). Per-wave FIFO invariant: at each
// boundary only B(t+2,h0/h1) (4 loads) outstanding. Writes bf16 z_pre at ZP_STRIDE.
__global__ __launch_bounds__(512, 2) void k_gemm(const unsigned short* __restrict__ A,
                                                 const unsigned short* __restrict__ Bm,
                                                 unsigned short* __restrict__ Zp) {
  __shared__ unsigned short SL[65536];        // A: [buf][256r][64c] @0; B same @32768 (shorts)
  const size_t K = H_DIM;
  int bid = blockIdx.x;
  int cpx = gridDim.x >> 3;                   // 1024/8 = 128, bijective (nwg%8==0)
  int swz = (bid & 7) * cpx + (bid >> 3);
  int tm = swz >> 6;                          // 16 M-tiles (XCD-consecutive share A panel)
  int tn = swz & 63;                          // 64 N-tiles
  int t = threadIdx.x;
  int lane = t & 63;
  int w = t >> 6;
  int wm = w >> 2, wn = w & 3;                // 2 x 4 wave grid; per-wave 128x64

  int rloc = lane & 15;
  int kc = lane >> 4;                         // 0..3: 8-elem K chunk within 32-K half
  int sw = rloc & 7;
  int ck0 = ((kc) ^ sw) << 3;                 // kk=0 swizzled chunk offset (shorts)
  int ck1 = ((4 + kc) ^ sw) << 3;             // kk=1
  int arow = (wm * 128 + rloc) << 6;          // + m*1024
  int brow = (wn * 64 + rloc) << 6;           // + n*1024 (+32768 base)

  // staging: thread t covers row (t>>3), phys chunk t&7 <- logical (t&7)^(row&7) (rule 21)
  int srow = t >> 3;
  int scs = ((t & 7) ^ (srow & 7)) << 3;
  const unsigned short* aS = A  + (size_t)(tm * 256 + srow) * K + scs;
  const unsigned short* bS = Bm + (size_t)(tn * 256 + srow) * K + scs;
  int dst = t * 8;                            // linear LDS dest within 64-row gload (shorts)

  f32x4 acc[8][4];
#pragma unroll
  for (int i = 0; i < 8; ++i)
#pragma unroll
    for (int j = 0; j < 4; ++j) { f32x4 z = {0.f, 0.f, 0.f, 0.f}; acc[i][j] = z; }

#define SAU(kt, h, bf) { const unsigned short* s = aS + (size_t)(h) * 128 * K + (size_t)(kt) * 64; \
    gload_lds16(s,          &SL[(bf) * 16384 + (h) * 8192 + dst]); \
    gload_lds16(s + 64 * K, &SL[(bf) * 16384 + (h) * 8192 + 4096 + dst]); }
#define SBU(kt, h, bf) { const unsigned short* s = bS + (size_t)(h) * 128 * K + (size_t)(kt) * 64; \
    gload_lds16(s,          &SL[32768 + (bf) * 16384 + (h) * 8192 + dst]); \
    gload_lds16(s + 64 * K, &SL[32768 + (bf) * 16384 + (h) * 8192 + 4096 + dst]); }

  // prologue: A(0,h0) A(0,h1) B(0,h0) B(0,h1) B(1,h0) B(1,h1) = 12 loads; allow B(1,*) in flight
  SAU(0, 0, 0) SAU(0, 1, 0) SBU(0, 0, 0) SBU(0, 1, 0) SBU(1, 0, 1) SBU(1, 1, 1)
  asm volatile("s_waitcnt vmcnt(4)" ::: "memory");
  __builtin_amdgcn_s_barrier();

  for (int tt = 0; tt < NKT; ++tt) {
    int bf = tt & 1;
    int ab = bf * 16384;
    int bb = 32768 + ab;
    bool stA = (tt + 1 < NKT);
    bool stB = (tt + 2 < NKT);
    bf16x8 a[4][2], b[4][2];
    // ---- P0: read a(m0-3,kk01)=8 + b(n0-1,kk01)=4; stage A(t+1,h0); MFMA Q0
#pragma unroll
    for (int m = 0; m < 4; ++m) {
      a[m][0] = *(const bf16x8*)&SL[ab + arow + m * 1024 + ck0];
      a[m][1] = *(const bf16x8*)&SL[ab + arow + m * 1024 + ck1];
    }
#pragma unroll
    for (int n = 0; n < 2; ++n) {
      b[n][0] = *(const bf16x8*)&SL[bb + brow + n * 1024 + ck0];
      b[n][1] = *(const bf16x8*)&SL[bb + brow + n * 1024 + ck1];
    }
    if (stA) SAU(tt + 1, 0, bf ^ 1)
    __builtin_amdgcn_s_barrier();
    __builtin_amdgcn_s_setprio(1);
#pragma unroll
    for (int kk = 0; kk < 2; ++kk)
#pragma unroll
      for (int m = 0; m < 4; ++m)
#pragma unroll
        for (int n = 0; n < 2; ++n)
          acc[m][n] = __builtin_amdgcn_mfma_f32_16x16x32_bf16(a[m][kk], b[n][kk], acc[m][n], 0, 0, 0);
    __builtin_amdgcn_s_setprio(0);
    __builtin_amdgcn_s_barrier();
    // ---- P1: read b(n2-3,kk01)=4; stage A(t+1,h1); MFMA Q1
#pragma unroll
    for (int n = 2; n < 4; ++n) {
      b[n][0] = *(const bf16x8*)&SL[bb + brow + n * 1024 + ck0];
      b[n][1] = *(const bf16x8*)&SL[bb + brow + n * 1024 + ck1];
    }
    if (stA) SAU(tt + 1, 1, bf ^ 1)
    __builtin_amdgcn_s_barrier();
    __builtin_amdgcn_s_setprio(1);
#pragma unroll
    for (int kk = 0; kk < 2; ++kk)
#pragma unroll
      for (int m = 0; m < 4; ++m)
#pragma unroll
        for (int n = 2; n < 4; ++n)
          acc[m][n] = __builtin_amdgcn_mfma_f32_16x16x32_bf16(a[m][kk], b[n][kk], acc[m][n], 0, 0, 0);
    __builtin_amdgcn_s_setprio(0);
    __builtin_amdgcn_s_barrier();
    // ---- P2: read a(m4-7,kk01)=8 (overwrite a regs); stage B(t+2,h0); MFMA Q2
#pragma unroll
    for (int m = 0; m < 4; ++m) {
      a[m][0] = *(const bf16x8*)&SL[ab + arow + (m + 4) * 1024 + ck0];
      a[m][1] = *(const bf16x8*)&SL[ab + arow + (m + 4) * 1024 + ck1];
    }
    if (stB) SBU(tt + 2, 0, bf)
    __builtin_amdgcn_s_barrier();
    __builtin_amdgcn_s_setprio(1);
#pragma unroll
    for (int kk = 0; kk < 2; ++kk)
#pragma unroll
      for (int m = 0; m < 4; ++m)
#pragma unroll
        for (int n = 0; n < 2; ++n)
          acc[m + 4][n] = __builtin_amdgcn_mfma_f32_16x16x32_bf16(a[m][kk], b[n][kk], acc[m + 4][n], 0, 0, 0);
    __builtin_amdgcn_s_setprio(0);
    __builtin_amdgcn_s_barrier();
    // ---- P3: no reads; stage B(t+2,h1); MFMA Q3; boundary counted wait
    if (stB) SBU(tt + 2, 1, bf)
    __builtin_amdgcn_s_barrier();
    __builtin_amdgcn_s_setprio(1);
#pragma unroll
    for (int kk = 0; kk < 2; ++kk)
#pragma unroll
      for (int m = 0; m < 4; ++m)
#pragma unroll
        for (int n = 2; n < 4; ++n)
          acc[m + 4][n] = __builtin_amdgcn_mfma_f32_16x16x32_bf16(a[m][kk], b[n][kk], acc[m + 4][n], 0, 0, 0);
    __builtin_amdgcn_s_setprio(0);
    if (tt < NKT - 2)       { asm volatile("s_waitcnt vmcnt(4)" ::: "memory"); }
    else if (tt == NKT - 2) { asm volatile("s_waitcnt vmcnt(0)" ::: "memory"); }
    __builtin_amdgcn_s_barrier();
  }
#undef SAU
#undef SBU
  // epilogue: C/D layout col=lane&15, row=(lane>>4)*4+reg [m89]; relu + bf16; stride 2L
  int colg = lane & 15, quad = lane >> 4;
  size_t rbase = (size_t)(tm * 256 + wm * 128 + quad * 4);
  int cbase = tn * 256 + wn * 64 + colg;
#pragma unroll
  for (int m = 0; m < 8; ++m)
#pragma unroll
    for (int n = 0; n < 4; ++n) {
      size_t rr = rbase + m * 16;
      int cc = cbase + n * 16;
#pragma unroll
      for (int r = 0; r < 4; ++r)
        Zp[(rr + r) * ZP_STRIDE + cc] = f32_to_bf16(fmaxf(acc[m][n][r], 0.0f));
    }
}

// ---------------- fused tail: collect (block-local) -> zero z row -> rank -> classify ->
//                  fp64-rescore AMBIG -> scatter z + LDS sel -> decode -> x_hat
// zpre row b lives in the first 32KB of fp32 z row b (ZP_STRIDE) -> all traffic block-local.
__global__ __launch_bounds__(256) void k_finish(const float* __restrict__ x,
                                                const float* __restrict__ Wenc,
                                                const unsigned short* __restrict__ WdT,
                                                float* __restrict__ zout,
                                                float* __restrict__ xhat) {
  int b = blockIdx.x;
  int t = threadIdx.x;
  __shared__ float xr[H_DIM];                 // 8 KB
  __shared__ float cv[CAND_CAP];
  __shared__ int   ci[CAND_CAP];
  __shared__ float s_b32;
  __shared__ unsigned int s_cnt, s_na, s_nin;
  __shared__ int    ai[AMBIG_CAP];
  __shared__ double ax[AMBIG_CAP];
  __shared__ float  sv[TOPK];
  __shared__ int    si[TOPK];

  const bf16x8* row = (const bf16x8*)((const unsigned short*)zout + (size_t)b * ZP_STRIDE);
  const float4* xv = (const float4*)(x + (size_t)b * H_DIM);
  for (int i = t; i < H_DIM / 4; i += 256) ((float4*)xr)[i] = xv[i];

  // collect with retry (block-local atomics only — R5 lesson)
  float thr = 2.3f;                           // v32 ~ N(2.89, 0.058) -> ~10 sigma safe
  for (int attempt = 0; attempt < 8; ++attempt) {
    if (t == 0) s_cnt = 0;
    __syncthreads();
    for (int i = t; i < L_DIM / 8; i += 256) {
      bf16x8 v = row[i];
#pragma unroll
      for (int q = 0; q < 8; ++q) {
        float f = bf16_to_f32((unsigned short)v[q]);
        if (f > thr) {
          unsigned int p = atomicAdd(&s_cnt, 1u);
          if (p < CAND_CAP) { ci[p] = i * 8 + q; cv[p] = f; }
        }
      }
    }
    __syncthreads();
    if (s_cnt >= 40 || thr <= 0.0f) break;
    thr -= 0.6f; if (thr < 0.0f) thr = 0.0f;
    __syncthreads();
  }
  int cnt = (int)(s_cnt < CAND_CAP ? s_cnt : CAND_CAP);

  // zero this block's z row (this block's zpre copy fully consumed above)
  __syncthreads();
  {
    float4 zz = {0.f, 0.f, 0.f, 0.f};
    float4* zr = (float4*)(zout + (size_t)b * L_DIM);
#pragma unroll
    for (int i = 0; i < L_DIM / 4 / 256; ++i) zr[i * 256 + t] = zz;
  }
  if (t == 0) { s_b32 = -1.0f; s_na = 0; s_nin = 0; }
  __syncthreads();

  bool tiny = (cnt < TOPK);                   // pathological: all candidates are in

  // rank (tie-break: equal value, lower slot counts as above) -> b32 = rank-31 value
  if (!tiny) {
    for (int i = t; i < cnt; i += 256) {
      float vi = cv[i]; int r = 0;
      for (int j = 0; j < cnt; ++j) { float vj = cv[j]; r += (vj > vi) || (vj == vi && j < i); }
      if (r == 31) s_b32 = vi;
    }
  }
  __syncthreads();
  float b32 = s_b32;

  // classify AMBIG
  if (!tiny) {
    for (int i = t; i < cnt; i += 256) {
      if (fabsf(cv[i] - b32) <= BAND) {
        unsigned int p = atomicAdd(&s_na, 1u);
        if (p < AMBIG_CAP) ai[p] = i;
      }
    }
  }
  __syncthreads();
  int na = (int)(s_na < AMBIG_CAP ? s_na : AMBIG_CAP);

  // fp64 rescore of AMBIG candidates (gather fp32 W_enc rows)
  int wv = t >> 6, lane = t & 63;
  for (int a = wv; a < na; a += 4) {
    int l = ci[ai[a]];
    const float4* wrow = (const float4*)(Wenc + (size_t)l * H_DIM);
    double acc = 0.0;
#pragma unroll
    for (int k8 = 0; k8 < 8; ++k8) {
      float4 ww = wrow[k8 * 64 + lane];
      float4 xx = ((const float4*)xr)[k8 * 64 + lane];
      acc += (double)ww.x * xx.x + (double)ww.y * xx.y + (double)ww.z * xx.z + (double)ww.w * xx.w;
    }
#pragma unroll
    for (int s = 32; s; s >>= 1) acc += __shfl_xor(acc, s, 64);
    if (lane == 0) ax[a] = acc;
  }
  __syncthreads();

  // emit SURE-IN (bf16-path value; |err| <= 0.03 << 0.113 threshold)
  for (int i = t; i < cnt; i += 256) {
    float vi = cv[i];
    if (tiny || vi - b32 > BAND) {
      unsigned int p = atomicAdd(&s_nin, 1u);
      sv[p] = vi; si[p] = ci[i];
      zout[(size_t)b * L_DIM + ci[i]] = vi;
    }
  }
  __syncthreads();
  int s0 = (int)s_nin;                        // <= 31 when !tiny; <= cnt < 32 when tiny

  // fill remaining 32-s0 slots from AMBIG by exact fp64 value (one wave, serial extract)
  if (t < 64) {
    int need = TOPK - s0; if (need < 0) need = 0;
    for (int k = 0; k < need; ++k) {
      double bv = -1.0e300; int bidx = 0x7fffffff; int bpos = -1;
      for (int a = lane; a < na; a += 64) {
        double v = ax[a]; int ii = ci[ai[a]];
        if (v > bv || (v == bv && ii < bidx)) { bv = v; bidx = ii; bpos = a; }
      }
#pragma unroll
      for (int sh = 32; sh; sh >>= 1) {
        double ov = __shfl_xor(bv, sh, 64);
        int oi = __shfl_xor(bidx, sh, 64);
        int op = __shfl_xor(bpos, sh, 64);
        if (ov > bv || (ov == bv && oi < bidx)) { bv = ov; bidx = oi; bpos = op; }
      }
      bool valid = (bpos >= 0) && (bv > -1.0e299);
      if (lane == 0) {
        sv[s0 + k] = valid ? (float)bv : 0.0f;
        si[s0 + k] = valid ? bidx : 0;
        if (valid) zout[(size_t)b * L_DIM + bidx] = (float)bv;
      }
      for (int a = lane; a < na; a += 64) if (a == bpos) ax[a] = -1.0e300;
    }
  }
  __syncthreads();

  // decode: x_hat row = sum_j sv[j] * WdT[si[j], :]
  float acc[8] = {0.f, 0.f, 0.f, 0.f, 0.f, 0.f, 0.f, 0.f};
  for (int j = 0; j < TOPK; ++j) {
    float vj = sv[j];
    bf16x8 ww = *(const bf16x8*)(WdT + (size_t)si[j] * H_DIM + t * 8);
#pragma unroll
    for (int i = 0; i < 8; ++i) acc[i] += vj * bf16_to_f32((unsigned short)ww[i]);
  }
  float4 o0 = {acc[0], acc[1], acc[2], acc[3]};
  float4 o1 = {acc[4], acc[5], acc[6], acc[7]};
  float4* op = (float4*)(xhat + (size_t)b * H_DIM + t * 8);
  op[0] = o0; op[1] = o1;
}

extern "C" void kernel_launch(void* const* d_in, const int* in_sizes, int n_in,
                              void* d_out, int out_size, void* d_ws, size_t ws_size,
                              hipStream_t stream) {
  const float* x    = (const float*)d_in[0];
  const float* Wenc = (const float*)d_in[1];
  const float* Wdec = (const float*)d_in[2];
  // d_in[3] = topk (=32), hardcoded

  float* xhat = (float*)d_out;
  float* z    = (float*)d_out + (size_t)B_ROWS * H_DIM;

  char* ws = (char*)d_ws;
  if (ws_size < 150994944u) return;  // need 144 MB scratch
  unsigned short* xbf    = (unsigned short*)(ws);                 // 16,777,216 B
  unsigned short* Wencbf = (unsigned short*)(ws + 16777216);      // 67,108,864 B
  unsigned short* WdT    = (unsigned short*)(ws + 83886080);      // 67,108,864 B

  unsigned short* zpre = (unsigned short*)z;                      // bf16, stride ZP_STRIDE

  k_convert<<<(2097152 + 255) / 256, 256, 0, stream>>>(x, xbf, 2097152);
  k_convert<<<(8388608 + 255) / 256, 256, 0, stream>>>(Wenc, Wencbf, 8388608);
  k_transpose<<<8192, 256, 0, stream>>>(Wdec, WdT);
  k_gemm<<<1024, 512, 0, stream>>>(xbf, Wencbf, zpre);            // bf16 relu'd z_pre
  k_finish<<<B_ROWS, 256, 0, stream>>>(x, Wenc, WdT, z, xhat);
}